// Round 10
// baseline (192.894 us; speedup 1.0000x reference)
//
#include <hip/hip_runtime.h>

#define SC_LOG2 0.25503486f   // (1/sqrt(32)) * log2(e), folded into Q-weight staging

typedef __bf16 bf16x8 __attribute__((ext_vector_type(8)));
typedef __bf16 bf16x2 __attribute__((ext_vector_type(2)));
typedef float f32x4 __attribute__((ext_vector_type(4)));
typedef unsigned int u32x4 __attribute__((ext_vector_type(4)));

union FragU { u32x4 u; bf16x8 b; };
struct F8 { float4 lo, hi; };

__device__ __forceinline__ unsigned short f2bf(float f) {
  return __builtin_bit_cast(unsigned short, (__bf16)f);
}
__device__ __forceinline__ unsigned int pkbf(float a, float b) {
  bf16x2 v = { (__bf16)a, (__bf16)b };
  return __builtin_bit_cast(unsigned int, v);
}
__device__ __forceinline__ F8 ldf8(const float* p) {
  F8 r; r.lo = *(const float4*)p; r.hi = *(const float4*)(p + 4); return r;
}
__device__ __forceinline__ void cv8s(unsigned short* d, const F8& v, float s) {
  u32x4 o;
  o.x = pkbf(v.lo.x * s, v.lo.y * s);
  o.y = pkbf(v.lo.z * s, v.lo.w * s);
  o.z = pkbf(v.hi.x * s, v.hi.y * s);
  o.w = pkbf(v.hi.z * s, v.hi.w * s);
  *(u32x4*)d = o;
}
__device__ __forceinline__ void cv8n(unsigned short* d, const F8& v) {
  u32x4 o;
  o.x = pkbf(v.lo.x, v.lo.y);
  o.y = pkbf(v.lo.z, v.lo.w);
  o.z = pkbf(v.hi.x, v.hi.y);
  o.w = pkbf(v.hi.z, v.hi.w);
  *(u32x4*)d = o;
}

__device__ __forceinline__ void glds16(const void* g, void* l) {
  __builtin_amdgcn_global_load_lds(
      (const __attribute__((address_space(1))) unsigned int*)g,
      (__attribute__((address_space(3))) unsigned int*)l, 16, 0, 0);
}

// ---------------- GEMM1: QKV projection (128x128 tiles), fp32 inputs converted in staging ----
// Virtual A = [x_r || x_i] (4096 x 512).  Virtual W1 rows (1536 x 512), routed+signed on the fly:
//   [0,256): qr=[Wq_r,-Wq_i]*SC  [256,512): qi=[Wq_i,Wq_r]*SC
//   [512,768): kr=[Wkv_r,-Wkv_i]  [768,1024): ki=[Wkv_i,Wkv_r]
//   [1024,1280): vr=[Wkv_r(256+o),-Wkv_i(256+o)]  [1280,1536): vi=[Wkv_i(256+o),Wkv_r(256+o)]
// LDS: A [4 kg][128 m][8] at lds[0], B [4 kg][128 o][8] at lds[4096].  BK=32, 16 K-steps.
__global__ __launch_bounds__(256) void gemm_qkv(const float* __restrict__ xr,
                                                const float* __restrict__ xi,
                                                const float* __restrict__ Wq_r,
                                                const float* __restrict__ Wq_i,
                                                const float* __restrict__ Wkv_r,
                                                const float* __restrict__ Wkv_i,
                                                unsigned short* __restrict__ Qr,
                                                unsigned short* __restrict__ Qi,
                                                unsigned short* __restrict__ Kr,
                                                unsigned short* __restrict__ Ki,
                                                unsigned short* __restrict__ Vrt,
                                                unsigned short* __restrict__ Vit) {
  __shared__ __align__(16) unsigned short lds[8448];   // gemm: 8192; V-transpose: [64][132]
  unsigned short* ldsB = lds + 4096;
  int bid = blockIdx.x;
  int m0 = (bid / 12) * 128, o0 = (bid % 12) * 128;
  int t = threadIdx.x;
  int lane = t & 63, w = t >> 6;
  int l15 = lane & 15, g = lane >> 4;
  int wm = w >> 1, wn = w & 1;

  // per-thread staging sources
  int cb = (t >> 7) * 8;                       // col base within 32-col window (0 or 8)
  int arow = m0 + (t & 127);
  const float* xa_lo = xr + (size_t)arow * 256 + cb;
  const float* xa_hi = xi + (size_t)arow * 256 + cb;
  int wrow = o0 + (t & 127);
  int sec = wrow >> 8, o = wrow & 255;
  const float *wlo, *whi; float hsgn;
  switch (sec) {
    case 0:  wlo = Wq_r + (size_t)o * 256;          whi = Wq_i + (size_t)o * 256;          hsgn = -1.f; break;
    case 1:  wlo = Wq_i + (size_t)o * 256;          whi = Wq_r + (size_t)o * 256;          hsgn =  1.f; break;
    case 2:  wlo = Wkv_r + (size_t)o * 256;         whi = Wkv_i + (size_t)o * 256;         hsgn = -1.f; break;
    case 3:  wlo = Wkv_i + (size_t)o * 256;         whi = Wkv_r + (size_t)o * 256;         hsgn =  1.f; break;
    case 4:  wlo = Wkv_r + (size_t)(256 + o) * 256; whi = Wkv_i + (size_t)(256 + o) * 256; hsgn = -1.f; break;
    default: wlo = Wkv_i + (size_t)(256 + o) * 256; whi = Wkv_r + (size_t)(256 + o) * 256; hsgn =  1.f; break;
  }
  float qsc = (wrow < 512) ? SC_LOG2 : 1.f;    // attention scale folded into Q rows
  float slo = qsc, shi = hsgn * qsc;
  wlo += cb; whi += cb;

  f32x4 acc[4][4];
#pragma unroll
  for (int i = 0; i < 4; ++i)
#pragma unroll
    for (int j = 0; j < 4; ++j) acc[i][j] = f32x4{0.f, 0.f, 0.f, 0.f};

  // software-pipelined staging: regs hold kt, loads for kt+1 issue under MFMA(kt)
  F8 ra0 = ldf8(xa_lo), ra1 = ldf8(xa_lo + 16);
  F8 rw0 = ldf8(wlo),   rw1 = ldf8(wlo + 16);
  float s_cur = slo;

  for (int kt = 0; kt < 16; ++kt) {
    cv8n(lds + t * 8, ra0);
    cv8n(lds + 2048 + t * 8, ra1);
    cv8s(ldsB + t * 8, rw0, s_cur);
    cv8s(ldsB + 2048 + t * 8, rw1, s_cur);
    if (kt < 15) {
      int kn = kt + 1;
      int cw = (kn & 7) * 32;
      const float* as = (kn < 8 ? xa_lo : xa_hi) + cw;
      const float* ws = (kn < 8 ? wlo : whi) + cw;
      ra0 = ldf8(as); ra1 = ldf8(as + 16);
      rw0 = ldf8(ws); rw1 = ldf8(ws + 16);
      s_cur = (kn < 8) ? slo : shi;
    }
    __syncthreads();
    FragU a[4], b[4];
#pragma unroll
    for (int sm = 0; sm < 4; ++sm)
      a[sm].u = *(const u32x4*)(lds + g * 1024 + (wm * 64 + sm * 16 + l15) * 8);
#pragma unroll
    for (int sn = 0; sn < 4; ++sn)
      b[sn].u = *(const u32x4*)(ldsB + g * 1024 + (wn * 64 + sn * 16 + l15) * 8);
#pragma unroll
    for (int sm = 0; sm < 4; ++sm)
#pragma unroll
      for (int sn = 0; sn < 4; ++sn)
        acc[sm][sn] = __builtin_amdgcn_mfma_f32_16x16x32_bf16(a[sm].b, b[sn].b, acc[sm][sn], 0, 0, 0);
    __syncthreads();
  }

  if (o0 >= 1024) {
    // ---- V path: two 64-col halves through LDS transpose -> coalesced V^T stores ----
#pragma unroll
    for (int h = 0; h < 2; ++h) {
      if (wn == h) {
#pragma unroll
        for (int sn = 0; sn < 4; ++sn) {
          int ol = sn * 16 + l15;
#pragma unroll
          for (int sm = 0; sm < 4; ++sm)
#pragma unroll
            for (int r = 0; r < 4; ++r)
              lds[ol * 132 + wm * 64 + sm * 16 + 4 * g + r] = f2bf(acc[sm][sn][r]);
        }
      }
      __syncthreads();
      {
        int ol = t >> 2, mc = (t & 3) * 32;
        int oc = o0 + h * 64 + ol;
        int oo = oc & 255, dd = oo & 31, hh = oo >> 5;
        int bh = (m0 >> 11) * 8 + hh;
        int n = (m0 & 2047) + mc;
        unsigned short* dstp = ((oc >> 8) == 4 ? Vrt : Vit) + ((size_t)bh * 32 + dd) * 2048 + n;
#pragma unroll
        for (int q = 0; q < 4; ++q)
          *(u32x4*)(dstp + q * 8) = *(const u32x4*)(lds + ol * 132 + mc + q * 8);
      }
      if (h == 0) __syncthreads();
    }
  } else {
    // ---- Q/K path: row-major [bh][n][d] scatter stores ----
#pragma unroll
    for (int sn = 0; sn < 4; ++sn) {
      int oc = o0 + wn * 64 + sn * 16 + l15;
      int se = oc >> 8;
      int oo = oc & 255;
      int hh = oo >> 5, dd = oo & 31;
#pragma unroll
      for (int sm = 0; sm < 4; ++sm)
#pragma unroll
        for (int r = 0; r < 4; ++r) {
          int m = m0 + wm * 64 + sm * 16 + 4 * g + r;
          int b = m >> 11, n = m & 2047;
          int bh = b * 8 + hh;
          unsigned short v = f2bf(acc[sm][sn][r]);
          switch (se) {
            case 0:  Qr[((size_t)bh * 2048 + n) * 32 + dd] = v; break;
            case 1:  Qi[((size_t)bh * 2048 + n) * 32 + dd] = v; break;
            case 2:  Kr[((size_t)bh * 2048 + n) * 32 + dd] = v; break;
            default: Ki[((size_t)bh * 2048 + n) * 32 + dd] = v; break;
          }
        }
    }
  }
}

// ---------------- GEMM2: output projection (128x64 tiles), fp32 W2 converted in staging ----
// Virtual W2 rows interleaved: row 2c+0 = [Wo_r(c),-Wo_i(c)], row 2c+1 = [Wo_i(c),Wo_r(c)]
//   -> C[m][o] maps to out[m*512 + o] linearly ((...,DIM,2) interleaved output).
__global__ __launch_bounds__(256) void gemm_out(const unsigned short* __restrict__ Obf,
                                                const float* __restrict__ Wo_r,
                                                const float* __restrict__ Wo_i,
                                                float* __restrict__ out) {
  __shared__ __align__(16) unsigned short lds[6144];
  unsigned short* ldsB = lds + 4096;
  int t = threadIdx.x;
  int m0 = (blockIdx.x >> 3) * 128, o0 = (blockIdx.x & 7) * 64;
  int lane = t & 63, w = t >> 6;
  int l15 = lane & 15, g = lane >> 4;
  int wm = w >> 1, wn = w & 1;

  const unsigned short* ga = Obf + (size_t)(m0 + (t & 127)) * 512 + (t >> 7) * 8;
  int r2 = o0 + (t & 63);
  int comp = r2 & 1, o = r2 >> 1;
  const float* wlo = (comp ? Wo_i : Wo_r) + (size_t)o * 256 + (t >> 6) * 8;
  const float* whi = (comp ? Wo_r : Wo_i) + (size_t)o * 256 + (t >> 6) * 8;
  float shi = comp ? 1.f : -1.f;

  f32x4 acc[4][2];
#pragma unroll
  for (int i = 0; i < 4; ++i)
#pragma unroll
    for (int j = 0; j < 2; ++j) acc[i][j] = f32x4{0.f, 0.f, 0.f, 0.f};

  F8 rw = ldf8(wlo);
  float s_cur = 1.f;

  for (int kt = 0; kt < 16; ++kt) {
    glds16(ga + kt * 32, lds + t * 8);
    glds16(ga + 16 + kt * 32, lds + 2048 + t * 8);
    cv8s(ldsB + t * 8, rw, s_cur);
    if (kt < 15) {
      int kn = kt + 1;
      const float* ws = (kn < 8 ? wlo : whi) + (kn & 7) * 32;
      rw = ldf8(ws);
      s_cur = (kn < 8) ? 1.f : shi;
    }
    __syncthreads();
    FragU a[4], b[2];
#pragma unroll
    for (int sm = 0; sm < 4; ++sm)
      a[sm].u = *(const u32x4*)(lds + g * 1024 + (wm * 64 + sm * 16 + l15) * 8);
#pragma unroll
    for (int sn = 0; sn < 2; ++sn)
      b[sn].u = *(const u32x4*)(ldsB + g * 512 + (wn * 32 + sn * 16 + l15) * 8);
#pragma unroll
    for (int sm = 0; sm < 4; ++sm)
#pragma unroll
      for (int sn = 0; sn < 2; ++sn)
        acc[sm][sn] = __builtin_amdgcn_mfma_f32_16x16x32_bf16(a[sm].b, b[sn].b, acc[sm][sn], 0, 0, 0);
    __syncthreads();
  }

#pragma unroll
  for (int sm = 0; sm < 4; ++sm)
#pragma unroll
    for (int sn = 0; sn < 2; ++sn) {
      int oc = o0 + wn * 32 + sn * 16 + l15;
#pragma unroll
      for (int r = 0; r < 4; ++r) {
        int m = m0 + wm * 64 + sm * 16 + 4 * g + r;
        out[(size_t)m * 512 + oc] = acc[sm][sn][r];
      }
    }
}

// ---------------- fused 4-pass complex flash attention (unchanged from round 9) ----------------
// QBLK=32, KVBLK=64, no-max softmax, double-buffered K/V (issue-early staging), setprio MFMA.
// wave p: 0:(qr,kr,vr) 1:(-qr,ki,vr) 2:(qi,kr,vi) 3:(-qi,ki,vi);  o_r = O0 - O3 ; o_i = O1 + O2
__global__ __launch_bounds__(256) void attn(const unsigned short* __restrict__ Qr,
                                            const unsigned short* __restrict__ Qi,
                                            const unsigned short* __restrict__ Kr,
                                            const unsigned short* __restrict__ Ki,
                                            const unsigned short* __restrict__ Vrt,
                                            const unsigned short* __restrict__ Vit,
                                            unsigned short* __restrict__ Obf) {
  __shared__ __align__(16) char smem[49152];
  unsigned short* kv = (unsigned short*)smem;
  // shorts layout: K [buf][pass][4 kg][64 key][8d] : buf*4096 + pass*2048, region [0,8192)
  //                V [buf][pass][8 kg][32 d][8key] : 8192 + buf*4096 + pass*2048
  //                P per wave: 16384 + p*2048 : [2 kh][4 kg][32 q][8key]

  int bid = blockIdx.x;
  int bh = bid >> 6;
  int q0 = (bid & 63) * 32;
  int t = threadIdx.x;
  int p = t >> 6, lane = t & 63;
  int l15 = lane & 15, g = lane >> 4;

  const unsigned short* Qsel = (p & 2) ? Qi : Qr;
  FragU qf[2];
#pragma unroll
  for (int s = 0; s < 2; ++s)
    qf[s].u = *(const u32x4*)(Qsel + ((size_t)bh * 2048 + q0 + s * 16 + l15) * 32 + g * 8);
  if (p & 1) {
#pragma unroll
    for (int s = 0; s < 2; ++s) qf[s].u ^= 0x80008000u;  // negate Q instead of K
  }

  f32x4 acc[2][2];
#pragma unroll
  for (int s = 0; s < 2; ++s) { acc[s][0] = f32x4{0.f,0.f,0.f,0.f}; acc[s][1] = f32x4{0.f,0.f,0.f,0.f}; }
  float l_acc[2] = {0.f, 0.f};

  int i7 = t & 127;
  int passk = (t < 128) ? 0 : 1;
  const unsigned short* Ksrc = passk ? Ki : Kr;
  const unsigned short* Vsrc = passk ? Vit : Vrt;
  size_t kb0 = ((size_t)bh * 2048 + (i7 & 63)) * 32 + (i7 >> 6) * 8;
  size_t vb0 = ((size_t)bh * 32 + (i7 & 31)) * 2048 + (i7 >> 5) * 8;
  unsigned short* Pw = kv + 16384 + p * 2048;

  auto stage = [&](int ck, int nb) {
    int n0 = ck * 64;
    unsigned short* kd = kv + nb * 4096 + passk * 2048 + i7 * 8;
    unsigned short* vd = kv + 8192 + nb * 4096 + passk * 2048 + i7 * 8;
    glds16(Ksrc + kb0 + (size_t)n0 * 32, kd);
    glds16(Ksrc + kb0 + 16 + (size_t)n0 * 32, kd + 1024);
    glds16(Vsrc + vb0 + n0, vd);
    glds16(Vsrc + vb0 + 32 + n0, vd + 1024);
  };

  stage(0, 0);
  __syncthreads();

  for (int ck = 0; ck < 32; ++ck) {
    int cur = ck & 1;
    if (ck + 1 < 32) stage(ck + 1, cur ^ 1);   // issue-early into other buffer
    const unsigned short* Ktile = kv + cur * 4096 + ((p & 1) ? 2048 : 0);
    const unsigned short* Vtile = kv + 8192 + cur * 4096 + ((p & 2) ? 2048 : 0);

    // S^T = mfma(K, Q): per-lane q = l15, keys c*16 + 4g + {0..3}  (log2 domain)
    f32x4 st[4][2];
    __builtin_amdgcn_s_setprio(1);
#pragma unroll
    for (int c = 0; c < 4; ++c) {
      FragU kf; kf.u = *(const u32x4*)(Ktile + g * 512 + (c * 16 + l15) * 8);
#pragma unroll
      for (int s = 0; s < 2; ++s)
        st[c][s] = __builtin_amdgcn_mfma_f32_16x16x32_bf16(kf.b, qf[s].b, f32x4{0.f,0.f,0.f,0.f}, 0, 0, 0);
    }
    __builtin_amdgcn_s_setprio(0);

    // softmax numerator: P = exp2(S), per-lane l partial (no max, no rescale)
#pragma unroll
    for (int s = 0; s < 2; ++s) {
#pragma unroll
      for (int c = 0; c < 4; ++c) {
        float p0 = __builtin_amdgcn_exp2f(st[c][s][0]);
        float p1 = __builtin_amdgcn_exp2f(st[c][s][1]);
        float p2 = __builtin_amdgcn_exp2f(st[c][s][2]);
        float p3 = __builtin_amdgcn_exp2f(st[c][s][3]);
        l_acc[s] += (p0 + p1) + (p2 + p3);
        unsigned int w0 = pkbf(p0, p1);
        unsigned int w1 = pkbf(p2, p3);
        int eo = (c >> 1) * 1024 + (2 * (c & 1) + (g >> 1)) * 256 + (s * 16 + l15) * 8 + 4 * (g & 1);
        unsigned long long pv = (unsigned long long)w0 | ((unsigned long long)w1 << 32);
        *(unsigned long long*)(Pw + eo) = pv;
      }
    }

    // PV: O[s][h] += sum_kh P(16q x 32k) * V(32k x 16d)
    __builtin_amdgcn_s_setprio(1);
#pragma unroll
    for (int kh = 0; kh < 2; ++kh) {
      FragU vf0, vf1;
      vf0.u = *(const u32x4*)(Vtile + (4 * kh + g) * 256 + l15 * 8);
      vf1.u = *(const u32x4*)(Vtile + (4 * kh + g) * 256 + (16 + l15) * 8);
#pragma unroll
      for (int s = 0; s < 2; ++s) {
        FragU pf; pf.u = *(const u32x4*)(Pw + kh * 1024 + g * 256 + (s * 16 + l15) * 8);
        acc[s][0] = __builtin_amdgcn_mfma_f32_16x16x32_bf16(pf.b, vf0.b, acc[s][0], 0, 0, 0);
        acc[s][1] = __builtin_amdgcn_mfma_f32_16x16x32_bf16(pf.b, vf1.b, acc[s][1], 0, 0, 0);
      }
    }
    __builtin_amdgcn_s_setprio(0);
    __syncthreads();   // drains next-chunk staging; releases cur buffer for overwrite
  }

  // epilogue: reduce l across lane-groups, divide, cross-pass combine via LDS
  float linv[2];
#pragma unroll
  for (int s = 0; s < 2; ++s) {
    float lt = l_acc[s];
    lt += __shfl_xor(lt, 16);
    lt += __shfl_xor(lt, 32);
    linv[s] = 1.0f / lt;
  }
  float* ox = (float*)smem;
  if (p >= 2) {
    float* base = ox + ((p == 3) ? 0 : 1056);
#pragma unroll
    for (int s = 0; s < 2; ++s)
#pragma unroll
      for (int h = 0; h < 2; ++h)
#pragma unroll
        for (int r = 0; r < 4; ++r)
          base[(s * 16 + 4 * g + r) * 33 + 16 * h + l15] = acc[s][h][r] * __shfl(linv[s], 4 * g + r);
  }
  __syncthreads();
  if (p < 2) {
    const float* base = ox + ((p == 0) ? 0 : 1056);
    int coloff = (p == 0) ? 0 : 256;
    int b = bh >> 3, hh = bh & 7;
#pragma unroll
    for (int s = 0; s < 2; ++s)
#pragma unroll
      for (int h = 0; h < 2; ++h)
#pragma unroll
        for (int r = 0; r < 4; ++r) {
          float own = acc[s][h][r] * __shfl(linv[s], 4 * g + r);
          float part = base[(s * 16 + 4 * g + r) * 33 + 16 * h + l15];
          float res = (p == 0) ? (own - part) : (own + part);
          int q = q0 + s * 16 + 4 * g + r;
          Obf[((size_t)b * 2048 + q) * 512 + coloff + hh * 32 + 16 * h + l15] = f2bf(res);
        }
  }
}

extern "C" void kernel_launch(void* const* d_in, const int* in_sizes, int n_in,
                              void* d_out, int out_size, void* d_ws, size_t ws_size,
                              hipStream_t stream) {
  const float* xr    = (const float*)d_in[0];
  const float* xi    = (const float*)d_in[1];
  const float* Wq_r  = (const float*)d_in[2];
  const float* Wq_i  = (const float*)d_in[3];
  const float* Wkv_r = (const float*)d_in[4];
  const float* Wkv_i = (const float*)d_in[5];
  const float* Wo_r  = (const float*)d_in[6];
  const float* Wo_i  = (const float*)d_in[7];
  char* ws = (char*)d_ws;
  unsigned short* Qr  = (unsigned short*)(ws);
  unsigned short* Qi  = (unsigned short*)(ws + 2097152);
  unsigned short* Kr  = (unsigned short*)(ws + 4194304);
  unsigned short* Ki  = (unsigned short*)(ws + 6291456);
  unsigned short* Vrt = (unsigned short*)(ws + 8388608);
  unsigned short* Vit = (unsigned short*)(ws + 10485760);
  unsigned short* Obf = (unsigned short*)(ws + 12582912);
  float* out = (float*)d_out;

  gemm_qkv<<<dim3(384), dim3(256), 0, stream>>>(xr, xi, Wq_r, Wq_i, Wkv_r, Wkv_i,
                                                Qr, Qi, Kr, Ki, Vrt, Vit);
  attn<<<dim3(1024), dim3(256), 0, stream>>>(Qr, Qi, Kr, Ki, Vrt, Vit, Obf);
  gemm_out<<<dim3(256), dim3(256), 0, stream>>>(Obf, Wo_r, Wo_i, out);
}

// Round 11
// 180.496 us; speedup vs baseline: 1.0687x; 1.0687x over previous
//
#include <hip/hip_runtime.h>

#define SC_LOG2 0.25503486f   // (1/sqrt(32)) * log2(e), folded into Wq by prep_w

typedef __bf16 bf16x8 __attribute__((ext_vector_type(8)));
typedef __bf16 bf16x2 __attribute__((ext_vector_type(2)));
typedef float f32x4 __attribute__((ext_vector_type(4)));
typedef unsigned int u32x4 __attribute__((ext_vector_type(4)));

union FragU { u32x4 u; bf16x8 b; };

__device__ __forceinline__ unsigned short f2bf(float f) {
  return __builtin_bit_cast(unsigned short, (__bf16)f);
}
__device__ __forceinline__ unsigned int pkbf(float a, float b) {
  bf16x2 v = { (__bf16)a, (__bf16)b };
  return __builtin_bit_cast(unsigned int, v);
}

__device__ __forceinline__ void glds16(const void* g, void* l) {
  __builtin_amdgcn_global_load_lds(
      (const __attribute__((address_space(1))) unsigned int*)g,
      (__attribute__((address_space(3))) unsigned int*)l, 16, 0, 0);
}

// ---------------- prep: X = [x_r || x_i] as bf16 (4096 x 512) ----------------
__global__ __launch_bounds__(256) void prep_x(const float* __restrict__ xr,
                                              const float* __restrict__ xi,
                                              unsigned short* __restrict__ Xbf) {
  int idx = blockIdx.x * 256 + threadIdx.x;   // 262144 total
  int m = idx >> 6;
  int c8 = (idx & 63) << 3;
  const float* src = (c8 < 256) ? (xr + (size_t)m * 256 + c8)
                                : (xi + (size_t)m * 256 + (c8 - 256));
  float4 a = *(const float4*)src;
  float4 b = *(const float4*)(src + 4);
  u32x4 o;
  o.x = pkbf(a.x, a.y);
  o.y = pkbf(a.z, a.w);
  o.z = pkbf(b.x, b.y);
  o.w = pkbf(b.z, b.w);
  *(u32x4*)(Xbf + (size_t)m * 512 + c8) = o;
}

// ---------------- prep: combined weights Wc1 (1536 x 512), Wc2 (512 x 512) ----------------
// Wc1 rows: [0,256): qr=[Wq_r,-Wq_i]*SC  [256,512): qi=[Wq_i,Wq_r]*SC
//           [512,768): kr  [768,1024): ki  [1024,1280): vr  [1280,1536): vi
// Wc2 rows INTERLEAVED: row 2c+0 = [Wo_r(c),-Wo_i(c)], row 2c+1 = [Wo_i(c),Wo_r(c)]
__global__ __launch_bounds__(256) void prep_w(const float* __restrict__ Wq_r,
                                              const float* __restrict__ Wq_i,
                                              const float* __restrict__ Wkv_r,
                                              const float* __restrict__ Wkv_i,
                                              const float* __restrict__ Wo_r,
                                              const float* __restrict__ Wo_i,
                                              unsigned short* __restrict__ Wc1,
                                              unsigned short* __restrict__ Wc2) {
  int idx = blockIdx.x * 256 + threadIdx.x;   // 131072 total
  int row = idx >> 6;
  int c8 = (idx & 63) << 3;
  bool hi = (c8 >= 256);
  int cc = hi ? (c8 - 256) : c8;
  const float* lo_p; const float* hi_p; float hsgn;
  unsigned short* dst;
  if (row < 1536) {
    int sec = row >> 8, o = row & 255;
    switch (sec) {
      case 0:  lo_p = Wq_r + (size_t)o * 256;          hi_p = Wq_i + (size_t)o * 256;          hsgn = -1.f; break;
      case 1:  lo_p = Wq_i + (size_t)o * 256;          hi_p = Wq_r + (size_t)o * 256;          hsgn =  1.f; break;
      case 2:  lo_p = Wkv_r + (size_t)o * 256;         hi_p = Wkv_i + (size_t)o * 256;         hsgn = -1.f; break;
      case 3:  lo_p = Wkv_i + (size_t)o * 256;         hi_p = Wkv_r + (size_t)o * 256;         hsgn =  1.f; break;
      case 4:  lo_p = Wkv_r + (size_t)(256 + o) * 256; hi_p = Wkv_i + (size_t)(256 + o) * 256; hsgn = -1.f; break;
      default: lo_p = Wkv_i + (size_t)(256 + o) * 256; hi_p = Wkv_r + (size_t)(256 + o) * 256; hsgn =  1.f; break;
    }
    dst = Wc1 + (size_t)row * 512 + c8;
  } else {
    int r2 = row - 1536; int comp = r2 & 1; int o = r2 >> 1;
    lo_p = comp ? (Wo_i + (size_t)o * 256) : (Wo_r + (size_t)o * 256);
    hi_p = comp ? (Wo_r + (size_t)o * 256) : (Wo_i + (size_t)o * 256);
    hsgn = comp ? 1.f : -1.f;
    dst = Wc2 + (size_t)r2 * 512 + c8;
  }
  const float* src = hi ? hi_p : lo_p;
  float sgn = hi ? hsgn : 1.f;
  if (row < 512) sgn *= SC_LOG2;
  float4 a = *(const float4*)(src + cc);
  float4 b = *(const float4*)(src + cc + 4);
  u32x4 o4;
  o4.x = pkbf(a.x * sgn, a.y * sgn);
  o4.y = pkbf(a.z * sgn, a.w * sgn);
  o4.z = pkbf(b.x * sgn, b.y * sgn);
  o4.w = pkbf(b.z * sgn, b.w * sgn);
  *(u32x4*)dst = o4;
}

// ---------------- GEMM1: QKV projection, 128x64 tiles (768 blocks, 3/CU) ----------------
// LDS: A [4 kg][128 m][8] (8KB), B [4 kg][64 o][8] (4KB); V-transpose scratch overlays.
__global__ __launch_bounds__(256) void gemm_qkv(const unsigned short* __restrict__ Xbf,
                                                const unsigned short* __restrict__ Wc1,
                                                unsigned short* __restrict__ Qr,
                                                unsigned short* __restrict__ Qi,
                                                unsigned short* __restrict__ Kr,
                                                unsigned short* __restrict__ Ki,
                                                unsigned short* __restrict__ Vrt,
                                                unsigned short* __restrict__ Vit) {
  __shared__ __align__(16) unsigned short lds[8448];   // gemm uses 6144; V-transpose [64][132]
  unsigned short* ldsB = lds + 4096;
  int bid = blockIdx.x;
  int m0 = (bid / 24) * 128, o0 = (bid % 24) * 64;
  int t = threadIdx.x;
  int lane = t & 63, w = t >> 6;
  int l15 = lane & 15, g = lane >> 4;
  int wm = w >> 1, wn = w & 1;

  const unsigned short* ga = Xbf + (size_t)(m0 + (t & 127)) * 512 + (t >> 7) * 8;
  const unsigned short* gw = Wc1 + (size_t)(o0 + (t & 63)) * 512 + (t >> 6) * 8;

  f32x4 acc[4][2];
#pragma unroll
  for (int i = 0; i < 4; ++i)
#pragma unroll
    for (int j = 0; j < 2; ++j) acc[i][j] = f32x4{0.f, 0.f, 0.f, 0.f};

  for (int kt = 0; kt < 16; ++kt) {
    glds16(ga + kt * 32, lds + t * 8);
    glds16(ga + 16 + kt * 32, lds + 2048 + t * 8);
    glds16(gw + kt * 32, ldsB + t * 8);
    __syncthreads();
    FragU a[4], b[2];
#pragma unroll
    for (int sm = 0; sm < 4; ++sm)
      a[sm].u = *(const u32x4*)(lds + g * 1024 + (wm * 64 + sm * 16 + l15) * 8);
#pragma unroll
    for (int sn = 0; sn < 2; ++sn)
      b[sn].u = *(const u32x4*)(ldsB + g * 512 + (wn * 32 + sn * 16 + l15) * 8);
#pragma unroll
    for (int sm = 0; sm < 4; ++sm)
#pragma unroll
      for (int sn = 0; sn < 2; ++sn)
        acc[sm][sn] = __builtin_amdgcn_mfma_f32_16x16x32_bf16(a[sm].b, b[sn].b, acc[sm][sn], 0, 0, 0);
    __syncthreads();
  }

  if (o0 >= 1024) {
    // ---- V path: LDS transpose (128m x 64o) -> coalesced V^T stores ----
#pragma unroll
    for (int sn = 0; sn < 2; ++sn) {
      int ol = wn * 32 + sn * 16 + l15;
#pragma unroll
      for (int sm = 0; sm < 4; ++sm)
#pragma unroll
        for (int r = 0; r < 4; ++r)
          lds[ol * 132 + wm * 64 + sm * 16 + 4 * g + r] = f2bf(acc[sm][sn][r]);
    }
    __syncthreads();
    int ol = t >> 2, mc = (t & 3) * 32;
    int oc = o0 + ol;
    int oo = oc & 255, dd = oo & 31, hh = oo >> 5;
    int bh = (m0 >> 11) * 8 + hh;
    int n = (m0 & 2047) + mc;
    unsigned short* dstp = ((oc >> 8) == 4 ? Vrt : Vit) + ((size_t)bh * 32 + dd) * 2048 + n;
#pragma unroll
    for (int q = 0; q < 4; ++q)
      *(u32x4*)(dstp + q * 8) = *(const u32x4*)(lds + ol * 132 + mc + q * 8);
  } else {
    // ---- Q/K path: row-major [bh][n][d] scatter stores ----
#pragma unroll
    for (int sn = 0; sn < 2; ++sn) {
      int oc = o0 + wn * 32 + sn * 16 + l15;
      int se = oc >> 8;
      int oo = oc & 255;
      int hh = oo >> 5, dd = oo & 31;
#pragma unroll
      for (int sm = 0; sm < 4; ++sm)
#pragma unroll
        for (int r = 0; r < 4; ++r) {
          int m = m0 + wm * 64 + sm * 16 + 4 * g + r;
          int b = m >> 11, n = m & 2047;
          int bh = b * 8 + hh;
          unsigned short v = f2bf(acc[sm][sn][r]);
          switch (se) {
            case 0:  Qr[((size_t)bh * 2048 + n) * 32 + dd] = v; break;
            case 1:  Qi[((size_t)bh * 2048 + n) * 32 + dd] = v; break;
            case 2:  Kr[((size_t)bh * 2048 + n) * 32 + dd] = v; break;
            default: Ki[((size_t)bh * 2048 + n) * 32 + dd] = v; break;
          }
        }
    }
  }
}

// ---------------- GEMM2: output projection, 64x64 tiles (512 blocks), linear store ----------------
__global__ __launch_bounds__(256) void gemm_out(const unsigned short* __restrict__ Obf,
                                                const unsigned short* __restrict__ Wc2,
                                                float* __restrict__ out) {
  __shared__ __align__(16) unsigned short lds[4096];
  int m0 = (blockIdx.x >> 3) * 64, o0 = (blockIdx.x & 7) * 64;
  int t = threadIdx.x;
  int lane = t & 63, w = t >> 6;
  int l15 = lane & 15, g = lane >> 4;
  int sm2 = (w >> 1) * 32, sn2 = (w & 1) * 32;
  const unsigned short* ga = Obf + (size_t)(m0 + (t & 63)) * 512 + (t >> 6) * 8;
  const unsigned short* gw = Wc2 + (size_t)(o0 + (t & 63)) * 512 + (t >> 6) * 8;
  f32x4 acc[2][2];
#pragma unroll
  for (int i = 0; i < 2; ++i)
#pragma unroll
    for (int j = 0; j < 2; ++j) acc[i][j] = f32x4{0.f, 0.f, 0.f, 0.f};
  for (int kt = 0; kt < 16; ++kt) {
    glds16(ga + kt * 32, lds + t * 8);
    glds16(gw + kt * 32, lds + 2048 + t * 8);
    __syncthreads();
    FragU a0, a1, b0, b1;
    a0.u = *(const u32x4*)(lds + g * 512 + (sm2 + l15) * 8);
    a1.u = *(const u32x4*)(lds + g * 512 + (sm2 + 16 + l15) * 8);
    b0.u = *(const u32x4*)(lds + 2048 + g * 512 + (sn2 + l15) * 8);
    b1.u = *(const u32x4*)(lds + 2048 + g * 512 + (sn2 + 16 + l15) * 8);
    acc[0][0] = __builtin_amdgcn_mfma_f32_16x16x32_bf16(a0.b, b0.b, acc[0][0], 0, 0, 0);
    acc[0][1] = __builtin_amdgcn_mfma_f32_16x16x32_bf16(a0.b, b1.b, acc[0][1], 0, 0, 0);
    acc[1][0] = __builtin_amdgcn_mfma_f32_16x16x32_bf16(a1.b, b0.b, acc[1][0], 0, 0, 0);
    acc[1][1] = __builtin_amdgcn_mfma_f32_16x16x32_bf16(a1.b, b1.b, acc[1][1], 0, 0, 0);
    __syncthreads();
  }
#pragma unroll
  for (int sm = 0; sm < 2; ++sm)
#pragma unroll
    for (int sn = 0; sn < 2; ++sn) {
      int o = o0 + sn2 + sn * 16 + l15;
#pragma unroll
      for (int r = 0; r < 4; ++r) {
        int m = m0 + sm2 + sm * 16 + 4 * g + r;
        out[(size_t)m * 512 + o] = acc[sm][sn][r];
      }
    }
}

// ---------------- fused 4-pass complex flash attention ----------------
// QBLK=32, KVBLK=32, no-max softmax, double-buffered K/V (24KB LDS -> 4 blocks/CU), setprio.
// wave p: 0:(qr,kr,vr) 1:(-qr,ki,vr) 2:(qi,kr,vi) 3:(-qi,ki,vi);  o_r = O0 - O3 ; o_i = O1 + O2
__global__ __launch_bounds__(256) void attn(const unsigned short* __restrict__ Qr,
                                            const unsigned short* __restrict__ Qi,
                                            const unsigned short* __restrict__ Kr,
                                            const unsigned short* __restrict__ Ki,
                                            const unsigned short* __restrict__ Vrt,
                                            const unsigned short* __restrict__ Vit,
                                            unsigned short* __restrict__ Obf) {
  __shared__ __align__(16) char smem[24576];
  unsigned short* kv = (unsigned short*)smem;
  // shorts layout: K [buf][pass][4 kg][32 key][8d] : buf*2048 + pass*1024, region [0,4096)
  //                V [buf][pass][4 kg][32 d][8key] : 4096 + buf*2048 + pass*1024
  //                P per wave: 8192 + p*1024 : [4 kg][32 q][8key]

  int bid = blockIdx.x;
  int bh = bid >> 6;
  int q0 = (bid & 63) * 32;
  int t = threadIdx.x;
  int p = t >> 6, lane = t & 63;
  int l15 = lane & 15, g = lane >> 4;

  const unsigned short* Qsel = (p & 2) ? Qi : Qr;
  FragU qf[2];
#pragma unroll
  for (int s = 0; s < 2; ++s)
    qf[s].u = *(const u32x4*)(Qsel + ((size_t)bh * 2048 + q0 + s * 16 + l15) * 32 + g * 8);
  if (p & 1) {
#pragma unroll
    for (int s = 0; s < 2; ++s) qf[s].u ^= 0x80008000u;  // negate Q instead of K
  }

  f32x4 acc[2][2];
#pragma unroll
  for (int s = 0; s < 2; ++s) { acc[s][0] = f32x4{0.f,0.f,0.f,0.f}; acc[s][1] = f32x4{0.f,0.f,0.f,0.f}; }
  float l_acc[2] = {0.f, 0.f};

  // staging: threads <128 stage (kr,vr), >=128 stage (ki,vi); 1 glds16 each for K and V
  int i7 = t & 127;
  int passk = (t < 128) ? 0 : 1;
  const unsigned short* Ksrc = passk ? Ki : Kr;
  const unsigned short* Vsrc = passk ? Vit : Vrt;
  size_t kb0 = ((size_t)bh * 2048 + (i7 & 31)) * 32 + (i7 >> 5) * 8;
  size_t vb0 = ((size_t)bh * 32 + (i7 & 31)) * 2048 + (i7 >> 5) * 8;
  unsigned short* Pw = kv + 8192 + p * 1024;

  auto stage = [&](int ck, int nb) {
    int n0 = ck * 32;
    glds16(Ksrc + kb0 + (size_t)n0 * 32, kv + nb * 2048 + passk * 1024 + i7 * 8);
    glds16(Vsrc + vb0 + n0, kv + 4096 + nb * 2048 + passk * 1024 + i7 * 8);
  };

  stage(0, 0);
  __syncthreads();

  for (int ck = 0; ck < 64; ++ck) {
    int cur = ck & 1;
    if (ck + 1 < 64) stage(ck + 1, cur ^ 1);   // issue-early into other buffer
    const unsigned short* Ktile = kv + cur * 2048 + ((p & 1) ? 1024 : 0);
    const unsigned short* Vtile = kv + 4096 + cur * 2048 + ((p & 2) ? 1024 : 0);

    // S^T = mfma(K, Q): per-lane q = l15, keys c*16 + 4g + {0..3}  (log2 domain)
    f32x4 st[2][2];
    __builtin_amdgcn_s_setprio(1);
#pragma unroll
    for (int c = 0; c < 2; ++c) {
      FragU kf; kf.u = *(const u32x4*)(Ktile + g * 256 + (c * 16 + l15) * 8);
#pragma unroll
      for (int s = 0; s < 2; ++s)
        st[c][s] = __builtin_amdgcn_mfma_f32_16x16x32_bf16(kf.b, qf[s].b, f32x4{0.f,0.f,0.f,0.f}, 0, 0, 0);
    }
    __builtin_amdgcn_s_setprio(0);

    // softmax numerator: P = exp2(S), per-lane l partial (no max, no rescale)
#pragma unroll
    for (int s = 0; s < 2; ++s) {
#pragma unroll
      for (int c = 0; c < 2; ++c) {
        float p0 = __builtin_amdgcn_exp2f(st[c][s][0]);
        float p1 = __builtin_amdgcn_exp2f(st[c][s][1]);
        float p2 = __builtin_amdgcn_exp2f(st[c][s][2]);
        float p3 = __builtin_amdgcn_exp2f(st[c][s][3]);
        l_acc[s] += (p0 + p1) + (p2 + p3);
        unsigned int w0 = pkbf(p0, p1);
        unsigned int w1 = pkbf(p2, p3);
        // keys c*16+4g+{0..3} -> kg' = 2c+(g>>1), slot 4(g&1)
        int eo = (2 * c + (g >> 1)) * 256 + (s * 16 + l15) * 8 + 4 * (g & 1);
        unsigned long long pv = (unsigned long long)w0 | ((unsigned long long)w1 << 32);
        *(unsigned long long*)(Pw + eo) = pv;
      }
    }

    // PV: O[s][h] += P(16q x 32k) * V(32k x 16d)
    __builtin_amdgcn_s_setprio(1);
    {
      FragU vf0, vf1;
      vf0.u = *(const u32x4*)(Vtile + g * 256 + l15 * 8);
      vf1.u = *(const u32x4*)(Vtile + g * 256 + (16 + l15) * 8);
#pragma unroll
      for (int s = 0; s < 2; ++s) {
        FragU pf; pf.u = *(const u32x4*)(Pw + g * 256 + (s * 16 + l15) * 8);
        acc[s][0] = __builtin_amdgcn_mfma_f32_16x16x32_bf16(pf.b, vf0.b, acc[s][0], 0, 0, 0);
        acc[s][1] = __builtin_amdgcn_mfma_f32_16x16x32_bf16(pf.b, vf1.b, acc[s][1], 0, 0, 0);
      }
    }
    __builtin_amdgcn_s_setprio(0);
    __syncthreads();   // drains next-chunk staging; releases cur buffer for overwrite
  }

  // epilogue: reduce l across lane-groups, divide, cross-pass combine via LDS
  float linv[2];
#pragma unroll
  for (int s = 0; s < 2; ++s) {
    float lt = l_acc[s];
    lt += __shfl_xor(lt, 16);
    lt += __shfl_xor(lt, 32);
    linv[s] = 1.0f / lt;
  }
  float* ox = (float*)smem;
  if (p >= 2) {
    float* base = ox + ((p == 3) ? 0 : 1056);
#pragma unroll
    for (int s = 0; s < 2; ++s)
#pragma unroll
      for (int h = 0; h < 2; ++h)
#pragma unroll
        for (int r = 0; r < 4; ++r)
          base[(s * 16 + 4 * g + r) * 33 + 16 * h + l15] = acc[s][h][r] * __shfl(linv[s], 4 * g + r);
  }
  __syncthreads();
  if (p < 2) {
    const float* base = ox + ((p == 0) ? 0 : 1056);
    int coloff = (p == 0) ? 0 : 256;
    int b = bh >> 3, hh = bh & 7;
#pragma unroll
    for (int s = 0; s < 2; ++s)
#pragma unroll
      for (int h = 0; h < 2; ++h)
#pragma unroll
        for (int r = 0; r < 4; ++r) {
          float own = acc[s][h][r] * __shfl(linv[s], 4 * g + r);
          float part = base[(s * 16 + 4 * g + r) * 33 + 16 * h + l15];
          float res = (p == 0) ? (own - part) : (own + part);
          int q = q0 + s * 16 + 4 * g + r;
          Obf[((size_t)b * 2048 + q) * 512 + coloff + hh * 32 + 16 * h + l15] = f2bf(res);
        }
  }
}

extern "C" void kernel_launch(void* const* d_in, const int* in_sizes, int n_in,
                              void* d_out, int out_size, void* d_ws, size_t ws_size,
                              hipStream_t stream) {
  const float* xr    = (const float*)d_in[0];
  const float* xi    = (const float*)d_in[1];
  const float* Wq_r  = (const float*)d_in[2];
  const float* Wq_i  = (const float*)d_in[3];
  const float* Wkv_r = (const float*)d_in[4];
  const float* Wkv_i = (const float*)d_in[5];
  const float* Wo_r  = (const float*)d_in[6];
  const float* Wo_i  = (const float*)d_in[7];
  char* ws = (char*)d_ws;
  unsigned short* Xbf = (unsigned short*)(ws);
  unsigned short* Wc1 = (unsigned short*)(ws + 4194304);
  unsigned short* Wc2 = (unsigned short*)(ws + 5767168);
  unsigned short* Qr  = (unsigned short*)(ws + 6291456);
  unsigned short* Qi  = (unsigned short*)(ws + 8388608);
  unsigned short* Kr  = (unsigned short*)(ws + 10485760);
  unsigned short* Ki  = (unsigned short*)(ws + 12582912);
  unsigned short* Vrt = (unsigned short*)(ws + 14680064);
  unsigned short* Vit = (unsigned short*)(ws + 16777216);
  unsigned short* Obf = (unsigned short*)(ws + 18874368);
  float* out = (float*)d_out;

  prep_x<<<dim3(1024), dim3(256), 0, stream>>>(xr, xi, Xbf);
  prep_w<<<dim3(512), dim3(256), 0, stream>>>(Wq_r, Wq_i, Wkv_r, Wkv_i, Wo_r, Wo_i, Wc1, Wc2);
  gemm_qkv<<<dim3(768), dim3(256), 0, stream>>>(Xbf, Wc1, Qr, Qi, Kr, Ki, Vrt, Vit);
  attn<<<dim3(1024), dim3(256), 0, stream>>>(Qr, Qi, Kr, Ki, Vrt, Vit, Obf);
  gemm_out<<<dim3(512), dim3(256), 0, stream>>>(Obf, Wc2, out);
}

// Round 12
// 179.409 us; speedup vs baseline: 1.0752x; 1.0061x over previous
//
#include <hip/hip_runtime.h>

#define SC_LOG2 0.25503486f   // (1/sqrt(32)) * log2(e), folded into Wq by prep_w

typedef __bf16 bf16x8 __attribute__((ext_vector_type(8)));
typedef __bf16 bf16x2 __attribute__((ext_vector_type(2)));
typedef float f32x4 __attribute__((ext_vector_type(4)));
typedef unsigned int u32x4 __attribute__((ext_vector_type(4)));

union FragU { u32x4 u; bf16x8 b; };

__device__ __forceinline__ unsigned short f2bf(float f) {
  return __builtin_bit_cast(unsigned short, (__bf16)f);
}
__device__ __forceinline__ unsigned int pkbf(float a, float b) {
  bf16x2 v = { (__bf16)a, (__bf16)b };
  return __builtin_bit_cast(unsigned int, v);
}

__device__ __forceinline__ void glds16(const void* g, void* l) {
  __builtin_amdgcn_global_load_lds(
      (const __attribute__((address_space(1))) unsigned int*)g,
      (__attribute__((address_space(3))) unsigned int*)l, 16, 0, 0);
}

// ---------------- prep: X = [x_r || x_i] as bf16 (4096 x 512) ----------------
__global__ __launch_bounds__(256) void prep_x(const float* __restrict__ xr,
                                              const float* __restrict__ xi,
                                              unsigned short* __restrict__ Xbf) {
  int idx = blockIdx.x * 256 + threadIdx.x;   // 262144 total
  int m = idx >> 6;
  int c8 = (idx & 63) << 3;
  const float* src = (c8 < 256) ? (xr + (size_t)m * 256 + c8)
                                : (xi + (size_t)m * 256 + (c8 - 256));
  float4 a = *(const float4*)src;
  float4 b = *(const float4*)(src + 4);
  u32x4 o;
  o.x = pkbf(a.x, a.y);
  o.y = pkbf(a.z, a.w);
  o.z = pkbf(b.x, b.y);
  o.w = pkbf(b.z, b.w);
  *(u32x4*)(Xbf + (size_t)m * 512 + c8) = o;
}

// ---------------- prep: combined weights Wc1 (1536 x 512), Wc2 (512 x 512) ----------------
// Wc1 rows: [0,256): qr=[Wq_r,-Wq_i]*SC  [256,512): qi=[Wq_i,Wq_r]*SC
//           [512,768): kr  [768,1024): ki  [1024,1280): vr  [1280,1536): vi
// Wc2 rows INTERLEAVED: row 2c+0 = [Wo_r(c),-Wo_i(c)], row 2c+1 = [Wo_i(c),Wo_r(c)]
__global__ __launch_bounds__(256) void prep_w(const float* __restrict__ Wq_r,
                                              const float* __restrict__ Wq_i,
                                              const float* __restrict__ Wkv_r,
                                              const float* __restrict__ Wkv_i,
                                              const float* __restrict__ Wo_r,
                                              const float* __restrict__ Wo_i,
                                              unsigned short* __restrict__ Wc1,
                                              unsigned short* __restrict__ Wc2) {
  int idx = blockIdx.x * 256 + threadIdx.x;   // 131072 total
  int row = idx >> 6;
  int c8 = (idx & 63) << 3;
  bool hi = (c8 >= 256);
  int cc = hi ? (c8 - 256) : c8;
  const float* lo_p; const float* hi_p; float hsgn;
  unsigned short* dst;
  if (row < 1536) {
    int sec = row >> 8, o = row & 255;
    switch (sec) {
      case 0:  lo_p = Wq_r + (size_t)o * 256;          hi_p = Wq_i + (size_t)o * 256;          hsgn = -1.f; break;
      case 1:  lo_p = Wq_i + (size_t)o * 256;          hi_p = Wq_r + (size_t)o * 256;          hsgn =  1.f; break;
      case 2:  lo_p = Wkv_r + (size_t)o * 256;         hi_p = Wkv_i + (size_t)o * 256;         hsgn = -1.f; break;
      case 3:  lo_p = Wkv_i + (size_t)o * 256;         hi_p = Wkv_r + (size_t)o * 256;         hsgn =  1.f; break;
      case 4:  lo_p = Wkv_r + (size_t)(256 + o) * 256; hi_p = Wkv_i + (size_t)(256 + o) * 256; hsgn = -1.f; break;
      default: lo_p = Wkv_i + (size_t)(256 + o) * 256; hi_p = Wkv_r + (size_t)(256 + o) * 256; hsgn =  1.f; break;
    }
    dst = Wc1 + (size_t)row * 512 + c8;
  } else {
    int r2 = row - 1536; int comp = r2 & 1; int o = r2 >> 1;
    lo_p = comp ? (Wo_i + (size_t)o * 256) : (Wo_r + (size_t)o * 256);
    hi_p = comp ? (Wo_r + (size_t)o * 256) : (Wo_i + (size_t)o * 256);
    hsgn = comp ? 1.f : -1.f;
    dst = Wc2 + (size_t)r2 * 512 + c8;
  }
  const float* src = hi ? hi_p : lo_p;
  float sgn = hi ? hsgn : 1.f;
  if (row < 512) sgn *= SC_LOG2;
  float4 a = *(const float4*)(src + cc);
  float4 b = *(const float4*)(src + cc + 4);
  u32x4 o4;
  o4.x = pkbf(a.x * sgn, a.y * sgn);
  o4.y = pkbf(a.z * sgn, a.w * sgn);
  o4.z = pkbf(b.x * sgn, b.y * sgn);
  o4.w = pkbf(b.z * sgn, b.w * sgn);
  *(u32x4*)dst = o4;
}

// ---------------- GEMM1: QKV projection, 128x64 tiles (768 blocks, 3/CU) ----------------
__global__ __launch_bounds__(256) void gemm_qkv(const unsigned short* __restrict__ Xbf,
                                                const unsigned short* __restrict__ Wc1,
                                                unsigned short* __restrict__ Qr,
                                                unsigned short* __restrict__ Qi,
                                                unsigned short* __restrict__ Kr,
                                                unsigned short* __restrict__ Ki,
                                                unsigned short* __restrict__ Vrt,
                                                unsigned short* __restrict__ Vit) {
  __shared__ __align__(16) unsigned short lds[8448];   // gemm uses 6144; V-transpose [64][132]
  unsigned short* ldsB = lds + 4096;
  int bid = blockIdx.x;
  int m0 = (bid / 24) * 128, o0 = (bid % 24) * 64;
  int t = threadIdx.x;
  int lane = t & 63, w = t >> 6;
  int l15 = lane & 15, g = lane >> 4;
  int wm = w >> 1, wn = w & 1;

  const unsigned short* ga = Xbf + (size_t)(m0 + (t & 127)) * 512 + (t >> 7) * 8;
  const unsigned short* gw = Wc1 + (size_t)(o0 + (t & 63)) * 512 + (t >> 6) * 8;

  f32x4 acc[4][2];
#pragma unroll
  for (int i = 0; i < 4; ++i)
#pragma unroll
    for (int j = 0; j < 2; ++j) acc[i][j] = f32x4{0.f, 0.f, 0.f, 0.f};

  for (int kt = 0; kt < 16; ++kt) {
    glds16(ga + kt * 32, lds + t * 8);
    glds16(ga + 16 + kt * 32, lds + 2048 + t * 8);
    glds16(gw + kt * 32, ldsB + t * 8);
    __syncthreads();
    FragU a[4], b[2];
#pragma unroll
    for (int sm = 0; sm < 4; ++sm)
      a[sm].u = *(const u32x4*)(lds + g * 1024 + (wm * 64 + sm * 16 + l15) * 8);
#pragma unroll
    for (int sn = 0; sn < 2; ++sn)
      b[sn].u = *(const u32x4*)(ldsB + g * 512 + (wn * 32 + sn * 16 + l15) * 8);
#pragma unroll
    for (int sm = 0; sm < 4; ++sm)
#pragma unroll
      for (int sn = 0; sn < 2; ++sn)
        acc[sm][sn] = __builtin_amdgcn_mfma_f32_16x16x32_bf16(a[sm].b, b[sn].b, acc[sm][sn], 0, 0, 0);
    __syncthreads();
  }

  if (o0 >= 1024) {
    // ---- V path: LDS transpose (128m x 64o) -> coalesced V^T stores ----
#pragma unroll
    for (int sn = 0; sn < 2; ++sn) {
      int ol = wn * 32 + sn * 16 + l15;
#pragma unroll
      for (int sm = 0; sm < 4; ++sm)
#pragma unroll
        for (int r = 0; r < 4; ++r)
          lds[ol * 132 + wm * 64 + sm * 16 + 4 * g + r] = f2bf(acc[sm][sn][r]);
    }
    __syncthreads();
    int ol = t >> 2, mc = (t & 3) * 32;
    int oc = o0 + ol;
    int oo = oc & 255, dd = oo & 31, hh = oo >> 5;
    int bh = (m0 >> 11) * 8 + hh;
    int n = (m0 & 2047) + mc;
    unsigned short* dstp = ((oc >> 8) == 4 ? Vrt : Vit) + ((size_t)bh * 32 + dd) * 2048 + n;
#pragma unroll
    for (int q = 0; q < 4; ++q)
      *(u32x4*)(dstp + q * 8) = *(const u32x4*)(lds + ol * 132 + mc + q * 8);
  } else {
    // ---- Q/K path: row-major [bh][n][d] scatter stores ----
#pragma unroll
    for (int sn = 0; sn < 2; ++sn) {
      int oc = o0 + wn * 32 + sn * 16 + l15;
      int se = oc >> 8;
      int oo = oc & 255;
      int hh = oo >> 5, dd = oo & 31;
#pragma unroll
      for (int sm = 0; sm < 4; ++sm)
#pragma unroll
        for (int r = 0; r < 4; ++r) {
          int m = m0 + wm * 64 + sm * 16 + 4 * g + r;
          int b = m >> 11, n = m & 2047;
          int bh = b * 8 + hh;
          unsigned short v = f2bf(acc[sm][sn][r]);
          switch (se) {
            case 0:  Qr[((size_t)bh * 2048 + n) * 32 + dd] = v; break;
            case 1:  Qi[((size_t)bh * 2048 + n) * 32 + dd] = v; break;
            case 2:  Kr[((size_t)bh * 2048 + n) * 32 + dd] = v; break;
            default: Ki[((size_t)bh * 2048 + n) * 32 + dd] = v; break;
          }
        }
    }
  }
}

// ---------------- GEMM2: output projection, 64x64 tiles (512 blocks), linear store ----------------
__global__ __launch_bounds__(256) void gemm_out(const unsigned short* __restrict__ Obf,
                                                const unsigned short* __restrict__ Wc2,
                                                float* __restrict__ out) {
  __shared__ __align__(16) unsigned short lds[4096];
  int m0 = (blockIdx.x >> 3) * 64, o0 = (blockIdx.x & 7) * 64;
  int t = threadIdx.x;
  int lane = t & 63, w = t >> 6;
  int l15 = lane & 15, g = lane >> 4;
  int sm2 = (w >> 1) * 32, sn2 = (w & 1) * 32;
  const unsigned short* ga = Obf + (size_t)(m0 + (t & 63)) * 512 + (t >> 6) * 8;
  const unsigned short* gw = Wc2 + (size_t)(o0 + (t & 63)) * 512 + (t >> 6) * 8;
  f32x4 acc[2][2];
#pragma unroll
  for (int i = 0; i < 2; ++i)
#pragma unroll
    for (int j = 0; j < 2; ++j) acc[i][j] = f32x4{0.f, 0.f, 0.f, 0.f};
  for (int kt = 0; kt < 16; ++kt) {
    glds16(ga + kt * 32, lds + t * 8);
    glds16(gw + kt * 32, lds + 2048 + t * 8);
    __syncthreads();
    FragU a0, a1, b0, b1;
    a0.u = *(const u32x4*)(lds + g * 512 + (sm2 + l15) * 8);
    a1.u = *(const u32x4*)(lds + g * 512 + (sm2 + 16 + l15) * 8);
    b0.u = *(const u32x4*)(lds + 2048 + g * 512 + (sn2 + l15) * 8);
    b1.u = *(const u32x4*)(lds + 2048 + g * 512 + (sn2 + 16 + l15) * 8);
    acc[0][0] = __builtin_amdgcn_mfma_f32_16x16x32_bf16(a0.b, b0.b, acc[0][0], 0, 0, 0);
    acc[0][1] = __builtin_amdgcn_mfma_f32_16x16x32_bf16(a0.b, b1.b, acc[0][1], 0, 0, 0);
    acc[1][0] = __builtin_amdgcn_mfma_f32_16x16x32_bf16(a1.b, b0.b, acc[1][0], 0, 0, 0);
    acc[1][1] = __builtin_amdgcn_mfma_f32_16x16x32_bf16(a1.b, b1.b, acc[1][1], 0, 0, 0);
    __syncthreads();
  }
#pragma unroll
  for (int sm = 0; sm < 2; ++sm)
#pragma unroll
    for (int sn = 0; sn < 2; ++sn) {
      int o = o0 + sn2 + sn * 16 + l15;
#pragma unroll
      for (int r = 0; r < 4; ++r) {
        int m = m0 + sm2 + sm * 16 + 4 * g + r;
        out[(size_t)m * 512 + o] = acc[sm][sn][r];
      }
    }
}

// ---------------- fused 4-pass complex flash attention ----------------
// QBLK=32, KVBLK=32, no-max softmax.  T4 pipeline: 3-buffer rotation, depth-2 prefetch,
// raw s_barrier + counted vmcnt(2) (never 0 in-loop) -> staging latency spans barriers.
// wave p: 0:(qr,kr,vr) 1:(-qr,ki,vr) 2:(qi,kr,vi) 3:(-qi,ki,vi);  o_r = O0 - O3 ; o_i = O1 + O2
__global__ __launch_bounds__(256) void attn(const unsigned short* __restrict__ Qr,
                                            const unsigned short* __restrict__ Qi,
                                            const unsigned short* __restrict__ Kr,
                                            const unsigned short* __restrict__ Ki,
                                            const unsigned short* __restrict__ Vrt,
                                            const unsigned short* __restrict__ Vit,
                                            unsigned short* __restrict__ Obf) {
  __shared__ __align__(16) char smem[32768];
  unsigned short* kv = (unsigned short*)smem;
  // shorts layout per buffer b (3 buffers x 4096):
  //   K: kv + b*4096 + pass*1024 : [4 kg][32 key][8 d]
  //   V: kv + b*4096 + 2048 + pass*1024 : [4 kg][32 d][8 key]
  // P per wave: kv + 12288 + p*1024 : [4 kg][32 q][8 key]

  int bid = blockIdx.x;
  int bh = bid >> 6;
  int q0 = (bid & 63) * 32;
  int t = threadIdx.x;
  int p = t >> 6, lane = t & 63;
  int l15 = lane & 15, g = lane >> 4;

  const unsigned short* Qsel = (p & 2) ? Qi : Qr;
  FragU qf[2];
#pragma unroll
  for (int s = 0; s < 2; ++s)
    qf[s].u = *(const u32x4*)(Qsel + ((size_t)bh * 2048 + q0 + s * 16 + l15) * 32 + g * 8);
  if (p & 1) {
#pragma unroll
    for (int s = 0; s < 2; ++s) qf[s].u ^= 0x80008000u;  // negate Q instead of K
  }

  f32x4 acc[2][2];
#pragma unroll
  for (int s = 0; s < 2; ++s) { acc[s][0] = f32x4{0.f,0.f,0.f,0.f}; acc[s][1] = f32x4{0.f,0.f,0.f,0.f}; }
  float l_acc[2] = {0.f, 0.f};

  // staging: threads <128 stage (kr,vr), >=128 stage (ki,vi); 1 glds16 each for K and V
  int i7 = t & 127;
  int passk = (t < 128) ? 0 : 1;
  const unsigned short* Ksrc = passk ? Ki : Kr;
  const unsigned short* Vsrc = passk ? Vit : Vrt;
  size_t kb0 = ((size_t)bh * 2048 + (i7 & 31)) * 32 + (i7 >> 5) * 8;
  size_t vb0 = ((size_t)bh * 32 + (i7 & 31)) * 2048 + (i7 >> 5) * 8;
  unsigned short* Pw = kv + 12288 + p * 1024;

  auto stage = [&](int ck, int nb) {
    int n0 = ck * 32;
    glds16(Ksrc + kb0 + (size_t)n0 * 32, kv + nb * 4096 + passk * 1024 + i7 * 8);
    glds16(Vsrc + vb0 + n0, kv + nb * 4096 + 2048 + passk * 1024 + i7 * 8);
  };

  stage(0, 0);
  stage(1, 1);

  int cur = 0;
  for (int ck = 0; ck < 64; ++ck) {
    // T4: wait only for chunk ck's 2 loads (ck+1's stay in flight across the barrier)
    if (ck < 63) asm volatile("s_waitcnt vmcnt(2)" ::: "memory");
    else         asm volatile("s_waitcnt vmcnt(0)" ::: "memory");
    __builtin_amdgcn_s_barrier();
    __builtin_amdgcn_sched_barrier(0);
    if (ck + 2 < 64) {
      int nb = (cur >= 1) ? cur - 1 : 2;     // (cur+2)%3: buffer retired at ck-1
      stage(ck + 2, nb);
    }
    const unsigned short* Ktile = kv + cur * 4096 + ((p & 1) ? 1024 : 0);
    const unsigned short* Vtile = kv + cur * 4096 + 2048 + ((p & 2) ? 1024 : 0);

    // S^T = mfma(K, Q): per-lane q = l15, keys c*16 + 4g + {0..3}  (log2 domain)
    f32x4 st[2][2];
    __builtin_amdgcn_s_setprio(1);
#pragma unroll
    for (int c = 0; c < 2; ++c) {
      FragU kf; kf.u = *(const u32x4*)(Ktile + g * 256 + (c * 16 + l15) * 8);
#pragma unroll
      for (int s = 0; s < 2; ++s)
        st[c][s] = __builtin_amdgcn_mfma_f32_16x16x32_bf16(kf.b, qf[s].b, f32x4{0.f,0.f,0.f,0.f}, 0, 0, 0);
    }
    __builtin_amdgcn_s_setprio(0);

    // softmax numerator: P = exp2(S), per-lane l partial (no max, no rescale)
#pragma unroll
    for (int s = 0; s < 2; ++s) {
#pragma unroll
      for (int c = 0; c < 2; ++c) {
        float p0 = __builtin_amdgcn_exp2f(st[c][s][0]);
        float p1 = __builtin_amdgcn_exp2f(st[c][s][1]);
        float p2 = __builtin_amdgcn_exp2f(st[c][s][2]);
        float p3 = __builtin_amdgcn_exp2f(st[c][s][3]);
        l_acc[s] += (p0 + p1) + (p2 + p3);
        unsigned int w0 = pkbf(p0, p1);
        unsigned int w1 = pkbf(p2, p3);
        // keys c*16+4g+{0..3} -> kg' = 2c+(g>>1), slot 4(g&1)
        int eo = (2 * c + (g >> 1)) * 256 + (s * 16 + l15) * 8 + 4 * (g & 1);
        unsigned long long pv = (unsigned long long)w0 | ((unsigned long long)w1 << 32);
        *(unsigned long long*)(Pw + eo) = pv;
      }
    }

    // PV: O[s][h] += P(16q x 32k) * V(32k x 16d)   (P is wave-private: no barrier needed)
    __builtin_amdgcn_s_setprio(1);
    {
      FragU vf0, vf1;
      vf0.u = *(const u32x4*)(Vtile + g * 256 + l15 * 8);
      vf1.u = *(const u32x4*)(Vtile + g * 256 + (16 + l15) * 8);
#pragma unroll
      for (int s = 0; s < 2; ++s) {
        FragU pf; pf.u = *(const u32x4*)(Pw + g * 256 + (s * 16 + l15) * 8);
        acc[s][0] = __builtin_amdgcn_mfma_f32_16x16x32_bf16(pf.b, vf0.b, acc[s][0], 0, 0, 0);
        acc[s][1] = __builtin_amdgcn_mfma_f32_16x16x32_bf16(pf.b, vf1.b, acc[s][1], 0, 0, 0);
      }
    }
    __builtin_amdgcn_s_setprio(0);
    cur = (cur == 2) ? 0 : cur + 1;
  }
  __syncthreads();   // full drain before smem reuse by epilogue

  // epilogue: reduce l across lane-groups, divide, cross-pass combine via LDS
  float linv[2];
#pragma unroll
  for (int s = 0; s < 2; ++s) {
    float lt = l_acc[s];
    lt += __shfl_xor(lt, 16);
    lt += __shfl_xor(lt, 32);
    linv[s] = 1.0f / lt;
  }
  float* ox = (float*)smem;
  if (p >= 2) {
    float* base = ox + ((p == 3) ? 0 : 1056);
#pragma unroll
    for (int s = 0; s < 2; ++s)
#pragma unroll
      for (int h = 0; h < 2; ++h)
#pragma unroll
        for (int r = 0; r < 4; ++r)
          base[(s * 16 + 4 * g + r) * 33 + 16 * h + l15] = acc[s][h][r] * __shfl(linv[s], 4 * g + r);
  }
  __syncthreads();
  if (p < 2) {
    const float* base = ox + ((p == 0) ? 0 : 1056);
    int coloff = (p == 0) ? 0 : 256;
    int b = bh >> 3, hh = bh & 7;
#pragma unroll
    for (int s = 0; s < 2; ++s)
#pragma unroll
      for (int h = 0; h < 2; ++h)
#pragma unroll
        for (int r = 0; r < 4; ++r) {
          float own = acc[s][h][r] * __shfl(linv[s], 4 * g + r);
          float part = base[(s * 16 + 4 * g + r) * 33 + 16 * h + l15];
          float res = (p == 0) ? (own - part) : (own + part);
          int q = q0 + s * 16 + 4 * g + r;
          Obf[((size_t)b * 2048 + q) * 512 + coloff + hh * 32 + 16 * h + l15] = f2bf(res);
        }
  }
}

extern "C" void kernel_launch(void* const* d_in, const int* in_sizes, int n_in,
                              void* d_out, int out_size, void* d_ws, size_t ws_size,
                              hipStream_t stream) {
  const float* xr    = (const float*)d_in[0];
  const float* xi    = (const float*)d_in[1];
  const float* Wq_r  = (const float*)d_in[2];
  const float* Wq_i  = (const float*)d_in[3];
  const float* Wkv_r = (const float*)d_in[4];
  const float* Wkv_i = (const float*)d_in[5];
  const float* Wo_r  = (const float*)d_in[6];
  const float* Wo_i  = (const float*)d_in[7];
  char* ws = (char*)d_ws;
  unsigned short* Xbf = (unsigned short*)(ws);
  unsigned short* Wc1 = (unsigned short*)(ws + 4194304);
  unsigned short* Wc2 = (unsigned short*)(ws + 5767168);
  unsigned short* Qr  = (unsigned short*)(ws + 6291456);
  unsigned short* Qi  = (unsigned short*)(ws + 8388608);
  unsigned short* Kr  = (unsigned short*)(ws + 10485760);
  unsigned short* Ki  = (unsigned short*)(ws + 12582912);
  unsigned short* Vrt = (unsigned short*)(ws + 14680064);
  unsigned short* Vit = (unsigned short*)(ws + 16777216);
  unsigned short* Obf = (unsigned short*)(ws + 18874368);
  float* out = (float*)d_out;

  prep_x<<<dim3(1024), dim3(256), 0, stream>>>(xr, xi, Xbf);
  prep_w<<<dim3(512), dim3(256), 0, stream>>>(Wq_r, Wq_i, Wkv_r, Wkv_i, Wo_r, Wo_i, Wc1, Wc2);
  gemm_qkv<<<dim3(768), dim3(256), 0, stream>>>(Xbf, Wc1, Qr, Qi, Kr, Ki, Vrt, Vit);
  attn<<<dim3(1024), dim3(256), 0, stream>>>(Qr, Qi, Kr, Ki, Vrt, Vit, Obf);
  gemm_out<<<dim3(512), dim3(256), 0, stream>>>(Obf, Wc2, out);
}